// Round 3
// baseline (237.881 us; speedup 1.0000x reference)
//
#include <hip/hip_runtime.h>

#define N_WORDS 16384
#define EMB 128
#define NROOTS 2048
#define EPS 1e-8f
#define LOG2_BOOST 0.5849625007211562f   // log2(1.5)

#define MV_BLOCKS 32768                  // 2048 roots * 16 blocks (8 rows/block)
#define HIST_BLOCKS 64

// ws layout (bytes):
//   [0,     8192)   counts  int[2048]   (memset 0)
//   [8192,  8196)   done    int         (memset 0)
//   [8196,  8200)   denom   float       (written by last hist block)
//   [16384, 81920)  roots   int[16384]
//   [81920, ...)    g       float[2048*128]

__global__ void k_fused(const float* __restrict__ M, const float* __restrict__ e,
                        const float* __restrict__ bias, float* __restrict__ g,
                        const int* __restrict__ wi, const int* __restrict__ rmap,
                        const float* __restrict__ w,
                        int* __restrict__ roots, int* __restrict__ counts,
                        int* __restrict__ done, float* __restrict__ denom) {
    if (blockIdx.x >= MV_BLOCKS) {
        // ---- histogram blocks ----
        __shared__ int amLast;
        __shared__ float scount[NROOTS];
        __shared__ float sred[4];
        int n = (blockIdx.x - MV_BLOCKS) * 256 + threadIdx.x;
        int r = rmap[wi[n]];
        roots[n] = r;
        atomicAdd(&counts[r], 1);
        __threadfence();                       // release: counts/roots visible
        __syncthreads();
        if (threadIdx.x == 0) amLast = (atomicAdd(done, 1) == HIST_BLOCKS - 1);
        __syncthreads();
        if (!amLast) return;
        __threadfence();                       // acquire: see all blocks' updates
        // last block: compute softmax denominator (hidden under matvec blocks)
        for (int i = threadIdx.x; i < NROOTS; i += 256)
            scount[i] = (float)(counts[i] - 1);
        __syncthreads();
        float acc = 0.f;
        for (int i = threadIdx.x; i < N_WORDS; i += 256)
            acc += fmaf(w[i], exp2f(scount[roots[i]] * LOG2_BOOST), EPS);
#pragma unroll
        for (int off = 32; off; off >>= 1) acc += __shfl_xor(acc, off, 64);
        int wave = threadIdx.x >> 6, lane = threadIdx.x & 63;
        if (lane == 0) sred[wave] = acc;
        __syncthreads();
        if (threadIdx.x == 0) *denom = sred[0] + sred[1] + sred[2] + sred[3];
        return;
    }
    // ---- matvec blocks: g[r] = M[r] @ e[r] + bias[r] ----
    int b = blockIdx.x;
    int r = b >> 4;                                           // 16 blocks per root
    int wave = threadIdx.x >> 6;
    int lane = threadIdx.x & 63;
    int row = ((b & 15) << 3) + (wave << 1) + (lane >> 5);    // 8 rows/block, 2 rows/wave
    int col = (lane & 31) << 2;                               // 32 lanes * float4 = 128 cols
    size_t rbase = (size_t)r << 7;
    const float4 m  = *(const float4*)(M + (rbase + row) * EMB + col);
    const float4 ee = *(const float4*)(e + rbase + col);
    float acc = fmaf(m.x, ee.x, fmaf(m.y, ee.y, fmaf(m.z, ee.z, m.w * ee.w)));
#pragma unroll
    for (int off = 16; off; off >>= 1) acc += __shfl_xor(acc, off, 64);  // 32-lane group
    if ((lane & 31) == 0) g[rbase + row] = acc + bias[rbase + row];
}

// one float4 per thread; scale by v/denom recomputed inline
__global__ void k_out(const float* __restrict__ g, const int* __restrict__ roots,
                      const int* __restrict__ counts, const float* __restrict__ w,
                      const float* __restrict__ denom, float4* __restrict__ out) {
    int idx = blockIdx.x * 256 + threadIdx.x;
    int n = idx >> 5;
    int r = roots[n];
    float c = (float)(counts[r] - 1);
    float v = fmaf(w[n], exp2f(c * LOG2_BOOST), EPS);
    float s = v / *denom;
    float4 gv = ((const float4*)(g + ((size_t)r << 7)))[idx & 31];
    gv.x *= s; gv.y *= s; gv.z *= s; gv.w *= s;
    out[idx] = gv;
}

extern "C" void kernel_launch(void* const* d_in, const int* in_sizes, int n_in,
                              void* d_out, int out_size, void* d_ws, size_t ws_size,
                              hipStream_t stream) {
    const float* emb  = (const float*)d_in[0];
    const float* M    = (const float*)d_in[1];
    const float* bias = (const float*)d_in[2];
    const float* attw = (const float*)d_in[3];
    const int*   wi   = (const int*)d_in[4];
    const int*   rmap = (const int*)d_in[5];
    float* out = (float*)d_out;

    char* ws = (char*)d_ws;
    int*   counts = (int*)(ws);
    int*   done   = (int*)(ws + 8192);
    float* denom  = (float*)(ws + 8196);
    int*   roots  = (int*)(ws + 16384);
    float* g      = (float*)(ws + 81920);

    hipMemsetAsync(ws, 0, 8200, stream);   // counts + done + denom
    k_fused<<<MV_BLOCKS + HIST_BLOCKS, 256, 0, stream>>>(M, emb, bias, g, wi, rmap, attw,
                                                         roots, counts, done, denom);
    k_out<<<N_WORDS * (EMB / 4) / 256, 256, 0, stream>>>(g, roots, counts, attw, denom, (float4*)out);
}